// Round 6
// baseline (310.579 us; speedup 1.0000x reference)
//
#include <hip/hip_runtime.h>
#include <hip/hip_bf16.h>

#define N_NODES 50000
#define DEG 16
#define NE 800000
#define HID 128
#define NH 32
#define ECH 64
#define NG 64
#define NSLOT 32
#define LN_EPS 1e-5f

typedef __bf16 bf16x8 __attribute__((ext_vector_type(8)));
typedef float f32x4 __attribute__((ext_vector_type(4)));

__device__ __forceinline__ unsigned short f2bf(float f) {
  unsigned int u = __float_as_uint(f);
  u += 0x7FFFu + ((u >> 16) & 1u);          // round-to-nearest-even
  return (unsigned short)(u >> 16);
}
__device__ __forceinline__ unsigned int pack2(float a, float b) {
  return (unsigned int)f2bf(a) | ((unsigned int)f2bf(b) << 16);
}
// sum-broadcast over the 16-lane DPP row via row_ror rotations
__device__ __forceinline__ float rowsum16(float v) {
  v += __int_as_float(__builtin_amdgcn_update_dpp(0, __float_as_int(v), 0x121, 0xF, 0xF, true));
  v += __int_as_float(__builtin_amdgcn_update_dpp(0, __float_as_int(v), 0x122, 0xF, 0xF, true));
  v += __int_as_float(__builtin_amdgcn_update_dpp(0, __float_as_int(v), 0x124, 0xF, 0xF, true));
  v += __int_as_float(__builtin_amdgcn_update_dpp(0, __float_as_int(v), 0x128, 0xF, 0xF, true));
  return v;
}

// ---------------------------------------------------------------- prep ------
__global__ void prep_kernel(const float* __restrict__ Wq, const float* __restrict__ Wkv,
                            const float* __restrict__ Wdk,
                            unsigned short* __restrict__ WBf,
                            unsigned short* __restrict__ Wdkf,
                            float* __restrict__ gsum) {
  int b = blockIdx.x, t = threadIdx.x;
  if (b < 16) {
    int n = b;
    for (int idx = t; idx < 2048; idx += 256) {
      int j = idx & 7, l = (idx >> 3) & 63, kk = idx >> 9;
      int col = n * 16 + (l & 15);
      int k = kk * 32 + (l >> 4) * 8 + j;
      float v = (col < HID) ? Wq[k * HID + col] : Wkv[k * HID + (col - HID)];
      WBf[((n * 4 + kk) * 64 + l) * 8 + j] = f2bf(v);
    }
  } else if (b < 24) {
    int n2 = b - 16;
    for (int idx = t; idx < 1024; idx += 256) {
      int j = idx & 7, l = (idx >> 3) & 63, kk = idx >> 9;
      int col = n2 * 16 + (l & 15);
      int k = kk * 32 + (l >> 4) * 8 + j;
      Wdkf[((n2 * 2 + kk) * 64 + l) * 8 + j] = f2bf(Wdk[k * HID + col]);
    }
  } else {
    int chunk = b - 24;                      // 8 blocks zero NG*NSLOT*HID floats
    const int tot = NG * NSLOT * HID / 8;    // 32768 per block
    for (int i = chunk * tot + t; i < (chunk + 1) * tot; i += 256)
      gsum[i] = 0.0f;
  }
}

// ------------------------------------------------------------- node pass ----
__global__ __launch_bounds__(256) void node_kernel(
    const float* __restrict__ x, const float* __restrict__ bq,
    const float* __restrict__ bkv, const float* __restrict__ lng,
    const float* __restrict__ lnb, const unsigned short* __restrict__ WBf,
    float* __restrict__ qout, unsigned short* __restrict__ kout) {
  __shared__ __align__(16) unsigned short xn[64 * HID];
  int t = threadIdx.x;
  int node0 = blockIdx.x * 64;
  {
    int row = t >> 2, q4 = t & 3;
    int c0 = q4 * 32;
    int node = node0 + row;
    float v[32];
    if (node < N_NODES) {
      const float4* xp = (const float4*)(x + node * HID + c0);
#pragma unroll
      for (int i = 0; i < 8; i++) {
        float4 f = xp[i];
        v[4 * i] = f.x; v[4 * i + 1] = f.y; v[4 * i + 2] = f.z; v[4 * i + 3] = f.w;
      }
    } else {
#pragma unroll
      for (int i = 0; i < 32; i++) v[i] = 0.f;
    }
    float s = 0.f;
#pragma unroll
    for (int i = 0; i < 32; i++) s += v[i];
    s += __shfl_xor(s, 1); s += __shfl_xor(s, 2);
    float m = s * (1.0f / HID);
    float sq = 0.f;
#pragma unroll
    for (int i = 0; i < 32; i++) { float d = v[i] - m; sq += d * d; }
    sq += __shfl_xor(sq, 1); sq += __shfl_xor(sq, 2);
    float rstd = rsqrtf(sq * (1.0f / HID) + LN_EPS);
#pragma unroll
    for (int ch = 0; ch < 4; ch++) {
      float w0[8];
#pragma unroll
      for (int j = 0; j < 8; j++) {
        int c = c0 + ch * 8 + j;
        w0[j] = (v[ch * 8 + j] - m) * rstd * lng[c] + lnb[c];
      }
      uint4 u;
      u.x = pack2(w0[0], w0[1]); u.y = pack2(w0[2], w0[3]);
      u.z = pack2(w0[4], w0[5]); u.w = pack2(w0[6], w0[7]);
      int byte = row * 256 + ((c0 * 2 + ch * 16) ^ ((row & 7) << 4));
      *(uint4*)((char*)xn + byte) = u;
    }
  }
  __syncthreads();
  int w = t >> 6, l = t & 63;
  int arow = w * 16 + (l & 15);
  bf16x8 a[4];
#pragma unroll
  for (int kk = 0; kk < 4; kk++) {
    int byte = arow * 256 + ((kk * 64 + (l >> 4) * 16) ^ ((arow & 7) << 4));
    a[kk] = *(const bf16x8*)((const char*)xn + byte);
  }
  f32x4 acc[16];
#pragma unroll
  for (int n = 0; n < 16; n++) acc[n] = (f32x4){0.f, 0.f, 0.f, 0.f};
#pragma unroll
  for (int n = 0; n < 16; n++)
#pragma unroll
    for (int kk = 0; kk < 4; kk++) {
      bf16x8 bfr = *(const bf16x8*)(WBf + ((n * 4 + kk) * 64 + l) * 8);
      acc[n] = __builtin_amdgcn_mfma_f32_16x16x32_bf16(a[kk], bfr, acc[n], 0, 0, 0);
    }
#pragma unroll
  for (int n = 0; n < 16; n++) {
    int col = n * 16 + (l & 15);
    float bias = (col < HID) ? bq[col] : bkv[col - HID];
#pragma unroll
    for (int r = 0; r < 4; r++) {
      int node = node0 + w * 16 + (l >> 4) * 4 + r;
      if (node < N_NODES) {
        float vv = acc[n][r] + bias;
        if (col < HID) qout[node * HID + col] = vv;
        else kout[node * HID + (col - HID)] = f2bf(vv);
      }
    }
  }
}

// ------------------------------------------------------------- edge pass ----
// 4 nodes (64 edges) / block, 1 node / wave. All broadcast operands (x, q,
// bdk, ln params) staged into LDS once per block with coalesced loads; the
// n-loop touches only LDS + registers, so the only global-latency chains are
// the up-front k-gathers.
__global__ __launch_bounds__(256, 2) void edge_kernel(
    const float* __restrict__ x, const float* __restrict__ ea,
    const int* __restrict__ src_arr, const int* __restrict__ batch,
    const float* __restrict__ bdk, const float* __restrict__ lng,
    const float* __restrict__ lnb, const float* __restrict__ qg,
    const unsigned short* __restrict__ kbf,
    const unsigned short* __restrict__ Wdkf, float* __restrict__ gsum) {
  __shared__ __align__(16) unsigned short wdk_s[8 * 2 * 64 * 8];  // 16 KB
  __shared__ __align__(16) float xq_s[8 * HID];   // [0..3]=x rows, [4..7]=q rows
  __shared__ __align__(16) float prm_s[3 * HID];  // bdk | lng | lnb
  __shared__ __align__(16) float h_s[4 * 132];
  __shared__ int b4[4];
  int t = threadIdx.x;
  int node0 = blockIdx.x * 4;
  int w = t >> 6, l = t & 63, el = l & 15, eh = l >> 4;
  int ni = node0 + w;
  size_t e0n = (size_t)ni * DEG;

  // ---- stage broadcast operands (coalesced) -------------------------------
  xq_s[t]       = x[(size_t)node0 * HID + t];
  xq_s[256 + t] = x[(size_t)node0 * HID + 256 + t];
  xq_s[512 + t] = qg[(size_t)node0 * HID + t];
  xq_s[768 + t] = qg[(size_t)node0 * HID + 256 + t];
  if (t < HID) { prm_s[t] = bdk[t]; prm_s[HID + t] = lng[t]; prm_s[2 * HID + t] = lnb[t]; }
#pragma unroll
  for (int i = 0; i < 4; i++) {
    int idx = (i * 256 + t) * 8;
    *(uint4*)(wdk_s + idx) = *(const uint4*)(Wdkf + idx);
  }
  if (t < 4) b4[t] = batch[node0 + t];

  // ---- per-lane loads -----------------------------------------------------
  int srcn = src_arr[e0n + el];                       // 4-way broadcast
  const float* earow = ea + (e0n + el) * ECH + eh * 8;
  float4 ea00 = *(const float4*)(earow);
  float4 ea01 = *(const float4*)(earow + 4);
  float4 ea10 = *(const float4*)(earow + 32);
  float4 ea11 = *(const float4*)(earow + 36);
  const unsigned short* kr = kbf + (size_t)srcn * HID;
  uint2 kg[8];
#pragma unroll
  for (int n = 0; n < 8; n++) kg[n] = *(const uint2*)(kr + n * 16 + eh * 4);

  bf16x8 bfr[2];
  bfr[0][0] = (__bf16)ea00.x; bfr[0][1] = (__bf16)ea00.y;
  bfr[0][2] = (__bf16)ea00.z; bfr[0][3] = (__bf16)ea00.w;
  bfr[0][4] = (__bf16)ea01.x; bfr[0][5] = (__bf16)ea01.y;
  bfr[0][6] = (__bf16)ea01.z; bfr[0][7] = (__bf16)ea01.w;
  bfr[1][0] = (__bf16)ea10.x; bfr[1][1] = (__bf16)ea10.y;
  bfr[1][2] = (__bf16)ea10.z; bfr[1][3] = (__bf16)ea10.w;
  bfr[1][4] = (__bf16)ea11.x; bfr[1][5] = (__bf16)ea11.y;
  bfr[1][6] = (__bf16)ea11.z; bfr[1][7] = (__bf16)ea11.w;

  __syncthreads();                                    // LDS ready

  // ---- dk^T = Wdk^T (A) x ea^T (B) ----------------------------------------
  f32x4 acc[8];
#pragma unroll
  for (int n = 0; n < 8; n++) acc[n] = (f32x4){0.f, 0.f, 0.f, 0.f};
#pragma unroll
  for (int n = 0; n < 8; n++)
#pragma unroll
    for (int kk = 0; kk < 2; kk++) {
      bf16x8 af = *(const bf16x8*)(wdk_s + ((n * 2 + kk) * 64 + l) * 8);
      acc[n] = __builtin_amdgcn_mfma_f32_16x16x32_bf16(af, bfr[kk], acc[n], 0, 0, 0);
    }

  // ---- attention + message + residual (LDS/regs only) ---------------------
  f32x4 h1[8];
#pragma unroll
  for (int n = 0; n < 8; n++) {
    const int cb = n * 16 + eh * 4;
    f32x4 xv = *(const f32x4*)&xq_s[w * HID + cb];
    f32x4 qv = *(const f32x4*)&xq_s[512 + w * HID + cb];
    f32x4 bd = *(const f32x4*)&prm_s[cb];
    float k0 = __uint_as_float(kg[n].x << 16);
    float k1 = __uint_as_float(kg[n].x & 0xFFFF0000u);
    float k2 = __uint_as_float(kg[n].y << 16);
    float k3 = __uint_as_float(kg[n].y & 0xFFFF0000u);
    float d0 = acc[n][0] + bd[0];
    float d1 = acc[n][1] + bd[1];
    float d2 = acc[n][2] + bd[2];
    float d3 = acc[n][3] + bd[3];
    float s = qv[0] * k0 * d0 + qv[1] * k1 * d1 + qv[2] * k2 * d2 + qv[3] * k3 * d3;
    float at = s * __builtin_amdgcn_rcpf(1.0f + __expf(-s));   // silu
    float m0 = rowsum16(k0 * at);
    float m1 = rowsum16(k1 * at);
    float m2 = rowsum16(k2 * at);
    float m3 = rowsum16(k3 * at);
    h1[n] = (f32x4){xv[0] + m0 * 0.0625f, xv[1] + m1 * 0.0625f,
                    xv[2] + m2 * 0.0625f, xv[3] + m3 * 0.0625f};
  }
  // ---- LayerNorm over the node's 128 channels -----------------------------
  float ss = 0.f;
#pragma unroll
  for (int n = 0; n < 8; n++) ss += h1[n][0] + h1[n][1] + h1[n][2] + h1[n][3];
  ss += __shfl_xor(ss, 16); ss += __shfl_xor(ss, 32);
  float mean = ss * (1.0f / HID);
  float vv = 0.f;
#pragma unroll
  for (int n = 0; n < 8; n++) {
    float d0 = h1[n][0] - mean, d1 = h1[n][1] - mean;
    float d2 = h1[n][2] - mean, d3 = h1[n][3] - mean;
    vv += d0 * d0 + d1 * d1 + d2 * d2 + d3 * d3;
  }
  vv += __shfl_xor(vv, 16); vv += __shfl_xor(vv, 32);
  float rstd = rsqrtf(vv * (1.0f / HID) + LN_EPS);
  if (el < 8) {                          // lane el writes n = el
    int n = el;
    const int cb = n * 16 + eh * 4;
    f32x4 g4 = *(const f32x4*)&prm_s[HID + cb];
    f32x4 bb = *(const f32x4*)&prm_s[2 * HID + cb];
    f32x4 xv = *(const f32x4*)&xq_s[w * HID + cb];
    f32x4 ho;
#pragma unroll
    for (int r = 0; r < 4; r++)
      ho[r] = xv[r] + (h1[n][r] - mean) * rstd * g4[r] + bb[r];
    *(f32x4*)&h_s[w * 132 + cb] = ho;
  }
  __syncthreads();
  if (t < HID) {                         // run-length-compress by graph
    int c = t;
    int slot = blockIdx.x & (NSLOT - 1);
    float accu = h_s[c];
#pragma unroll
    for (int nn = 1; nn < 4; nn++) {
      if (b4[nn] == b4[nn - 1]) accu += h_s[nn * 132 + c];
      else {
        atomicAdd(&gsum[(b4[nn - 1] * NSLOT + slot) * HID + c], accu);
        accu = h_s[nn * 132 + c];
      }
    }
    atomicAdd(&gsum[(b4[3] * NSLOT + slot) * HID + c], accu);
  }
}

// ------------------------------------------------ probe A: loads+MFMA only --
// Same staging/gather/MFMA structure as edge_kernel; attention/LN/aggregation
// removed. Results kept alive via a per-thread store to dead scratch.
__global__ __launch_bounds__(256, 2) void edge_probeA(
    const float* __restrict__ x, const float* __restrict__ ea,
    const int* __restrict__ src_arr, const int* __restrict__ batch,
    const float* __restrict__ qg, const unsigned short* __restrict__ kbf,
    const unsigned short* __restrict__ Wdkf, float* __restrict__ scratch) {
  __shared__ __align__(16) unsigned short wdk_s[8 * 2 * 64 * 8];
  __shared__ __align__(16) float xq_s[8 * HID];
  __shared__ int b4[4];
  int t = threadIdx.x;
  int node0 = blockIdx.x * 4;
  int w = t >> 6, l = t & 63, el = l & 15, eh = l >> 4;
  int ni = node0 + w;
  size_t e0n = (size_t)ni * DEG;

  xq_s[t]       = x[(size_t)node0 * HID + t];
  xq_s[256 + t] = x[(size_t)node0 * HID + 256 + t];
  xq_s[512 + t] = qg[(size_t)node0 * HID + t];
  xq_s[768 + t] = qg[(size_t)node0 * HID + 256 + t];
#pragma unroll
  for (int i = 0; i < 4; i++) {
    int idx = (i * 256 + t) * 8;
    *(uint4*)(wdk_s + idx) = *(const uint4*)(Wdkf + idx);
  }
  if (t < 4) b4[t] = batch[node0 + t];

  int srcn = src_arr[e0n + el];
  const float* earow = ea + (e0n + el) * ECH + eh * 8;
  float4 ea00 = *(const float4*)(earow);
  float4 ea01 = *(const float4*)(earow + 4);
  float4 ea10 = *(const float4*)(earow + 32);
  float4 ea11 = *(const float4*)(earow + 36);
  const unsigned short* kr = kbf + (size_t)srcn * HID;
  uint2 kg[8];
#pragma unroll
  for (int n = 0; n < 8; n++) kg[n] = *(const uint2*)(kr + n * 16 + eh * 4);

  bf16x8 bfr[2];
  bfr[0][0] = (__bf16)ea00.x; bfr[0][1] = (__bf16)ea00.y;
  bfr[0][2] = (__bf16)ea00.z; bfr[0][3] = (__bf16)ea00.w;
  bfr[0][4] = (__bf16)ea01.x; bfr[0][5] = (__bf16)ea01.y;
  bfr[0][6] = (__bf16)ea01.z; bfr[0][7] = (__bf16)ea01.w;
  bfr[1][0] = (__bf16)ea10.x; bfr[1][1] = (__bf16)ea10.y;
  bfr[1][2] = (__bf16)ea10.z; bfr[1][3] = (__bf16)ea10.w;
  bfr[1][4] = (__bf16)ea11.x; bfr[1][5] = (__bf16)ea11.y;
  bfr[1][6] = (__bf16)ea11.z; bfr[1][7] = (__bf16)ea11.w;

  __syncthreads();

  f32x4 acc[8];
#pragma unroll
  for (int n = 0; n < 8; n++) acc[n] = (f32x4){0.f, 0.f, 0.f, 0.f};
#pragma unroll
  for (int n = 0; n < 8; n++)
#pragma unroll
    for (int kk = 0; kk < 2; kk++) {
      bf16x8 af = *(const bf16x8*)(wdk_s + ((n * 2 + kk) * 64 + l) * 8);
      acc[n] = __builtin_amdgcn_mfma_f32_16x16x32_bf16(af, bfr[kk], acc[n], 0, 0, 0);
    }

  float live = 0.f;
  unsigned int kx = 0;
#pragma unroll
  for (int n = 0; n < 8; n++) {
    live += acc[n][0] + acc[n][1] + acc[n][2] + acc[n][3];
    kx ^= kg[n].x ^ kg[n].y;
  }
  live += __uint_as_float(kx) + xq_s[t] + xq_s[512 + (t & 511)] + (float)b4[w];
  scratch[(blockIdx.x * 256 + t) & 16383] = live;
}

// ------------------------------------- probe C: full minus DPP reductions ---
__global__ __launch_bounds__(256, 2) void edge_probeC(
    const float* __restrict__ x, const float* __restrict__ ea,
    const int* __restrict__ src_arr, const int* __restrict__ batch,
    const float* __restrict__ bdk, const float* __restrict__ lng,
    const float* __restrict__ lnb, const float* __restrict__ qg,
    const unsigned short* __restrict__ kbf,
    const unsigned short* __restrict__ Wdkf, float* __restrict__ scratch) {
  __shared__ __align__(16) unsigned short wdk_s[8 * 2 * 64 * 8];
  __shared__ __align__(16) float xq_s[8 * HID];
  __shared__ __align__(16) float prm_s[3 * HID];
  __shared__ __align__(16) float h_s[4 * 132];
  __shared__ int b4[4];
  int t = threadIdx.x;
  int node0 = blockIdx.x * 4;
  int w = t >> 6, l = t & 63, el = l & 15, eh = l >> 4;
  int ni = node0 + w;
  size_t e0n = (size_t)ni * DEG;

  xq_s[t]       = x[(size_t)node0 * HID + t];
  xq_s[256 + t] = x[(size_t)node0 * HID + 256 + t];
  xq_s[512 + t] = qg[(size_t)node0 * HID + t];
  xq_s[768 + t] = qg[(size_t)node0 * HID + 256 + t];
  if (t < HID) { prm_s[t] = bdk[t]; prm_s[HID + t] = lng[t]; prm_s[2 * HID + t] = lnb[t]; }
#pragma unroll
  for (int i = 0; i < 4; i++) {
    int idx = (i * 256 + t) * 8;
    *(uint4*)(wdk_s + idx) = *(const uint4*)(Wdkf + idx);
  }
  if (t < 4) b4[t] = batch[node0 + t];

  int srcn = src_arr[e0n + el];
  const float* earow = ea + (e0n + el) * ECH + eh * 8;
  float4 ea00 = *(const float4*)(earow);
  float4 ea01 = *(const float4*)(earow + 4);
  float4 ea10 = *(const float4*)(earow + 32);
  float4 ea11 = *(const float4*)(earow + 36);
  const unsigned short* kr = kbf + (size_t)srcn * HID;
  uint2 kg[8];
#pragma unroll
  for (int n = 0; n < 8; n++) kg[n] = *(const uint2*)(kr + n * 16 + eh * 4);

  bf16x8 bfr[2];
  bfr[0][0] = (__bf16)ea00.x; bfr[0][1] = (__bf16)ea00.y;
  bfr[0][2] = (__bf16)ea00.z; bfr[0][3] = (__bf16)ea00.w;
  bfr[0][4] = (__bf16)ea01.x; bfr[0][5] = (__bf16)ea01.y;
  bfr[0][6] = (__bf16)ea01.z; bfr[0][7] = (__bf16)ea01.w;
  bfr[1][0] = (__bf16)ea10.x; bfr[1][1] = (__bf16)ea10.y;
  bfr[1][2] = (__bf16)ea10.z; bfr[1][3] = (__bf16)ea10.w;
  bfr[1][4] = (__bf16)ea11.x; bfr[1][5] = (__bf16)ea11.y;
  bfr[1][6] = (__bf16)ea11.z; bfr[1][7] = (__bf16)ea11.w;

  __syncthreads();

  f32x4 acc[8];
#pragma unroll
  for (int n = 0; n < 8; n++) acc[n] = (f32x4){0.f, 0.f, 0.f, 0.f};
#pragma unroll
  for (int n = 0; n < 8; n++)
#pragma unroll
    for (int kk = 0; kk < 2; kk++) {
      bf16x8 af = *(const bf16x8*)(wdk_s + ((n * 2 + kk) * 64 + l) * 8);
      acc[n] = __builtin_amdgcn_mfma_f32_16x16x32_bf16(af, bfr[kk], acc[n], 0, 0, 0);
    }

  f32x4 h1[8];
#pragma unroll
  for (int n = 0; n < 8; n++) {
    const int cb = n * 16 + eh * 4;
    f32x4 xv = *(const f32x4*)&xq_s[w * HID + cb];
    f32x4 qv = *(const f32x4*)&xq_s[512 + w * HID + cb];
    f32x4 bd = *(const f32x4*)&prm_s[cb];
    float k0 = __uint_as_float(kg[n].x << 16);
    float k1 = __uint_as_float(kg[n].x & 0xFFFF0000u);
    float k2 = __uint_as_float(kg[n].y << 16);
    float k3 = __uint_as_float(kg[n].y & 0xFFFF0000u);
    float d0 = acc[n][0] + bd[0];
    float d1 = acc[n][1] + bd[1];
    float d2 = acc[n][2] + bd[2];
    float d3 = acc[n][3] + bd[3];
    float s = qv[0] * k0 * d0 + qv[1] * k1 * d1 + qv[2] * k2 * d2 + qv[3] * k3 * d3;
    float at = s * __builtin_amdgcn_rcpf(1.0f + __expf(-s));
    // NO rowsum16 here — this is the ablation
    float m0 = k0 * at, m1 = k1 * at, m2 = k2 * at, m3 = k3 * at;
    h1[n] = (f32x4){xv[0] + m0 * 0.0625f, xv[1] + m1 * 0.0625f,
                    xv[2] + m2 * 0.0625f, xv[3] + m3 * 0.0625f};
  }
  float ss = 0.f;
#pragma unroll
  for (int n = 0; n < 8; n++) ss += h1[n][0] + h1[n][1] + h1[n][2] + h1[n][3];
  ss += __shfl_xor(ss, 16); ss += __shfl_xor(ss, 32);
  float mean = ss * (1.0f / HID);
  float vv = 0.f;
#pragma unroll
  for (int n = 0; n < 8; n++) {
    float d0 = h1[n][0] - mean, d1 = h1[n][1] - mean;
    float d2 = h1[n][2] - mean, d3 = h1[n][3] - mean;
    vv += d0 * d0 + d1 * d1 + d2 * d2 + d3 * d3;
  }
  vv += __shfl_xor(vv, 16); vv += __shfl_xor(vv, 32);
  float rstd = rsqrtf(vv * (1.0f / HID) + LN_EPS);
  if (el < 8) {
    int n = el;
    const int cb = n * 16 + eh * 4;
    f32x4 g4 = *(const f32x4*)&prm_s[HID + cb];
    f32x4 bb = *(const f32x4*)&prm_s[2 * HID + cb];
    f32x4 xv = *(const f32x4*)&xq_s[w * HID + cb];
    f32x4 ho;
#pragma unroll
    for (int r = 0; r < 4; r++)
      ho[r] = xv[r] + (h1[n][r] - mean) * rstd * g4[r] + bb[r];
    *(f32x4*)&h_s[w * 132 + cb] = ho;
  }
  __syncthreads();
  if (t < HID) {
    int c = t;
    int slot = blockIdx.x & (NSLOT - 1);
    float accu = h_s[c];
#pragma unroll
    for (int nn = 1; nn < 4; nn++) {
      if (b4[nn] == b4[nn - 1]) accu += h_s[nn * 132 + c];
      else {
        atomicAdd(&scratch[((b4[nn - 1] * NSLOT + slot) * HID + c) & 16383], accu);
        accu = h_s[nn * 132 + c];
      }
    }
    atomicAdd(&scratch[((b4[3] * NSLOT + slot) * HID + c) & 16383], accu);
  }
}

// -------------------------------------------------------------- readout -----
__global__ void readout_kernel(const float* __restrict__ gsum,
                               const int* __restrict__ batch,
                               const float* __restrict__ Wout,
                               const float* __restrict__ bout,
                               float* __restrict__ out) {
  int g = blockIdx.x, l = threadIdx.x;
  int lo = 0, hi = N_NODES;
  while (lo < hi) { int mid = (lo + hi) >> 1; if (batch[mid] < g) lo = mid + 1; else hi = mid; }
  int lo2 = lo, hi2 = N_NODES;
  while (lo2 < hi2) { int mid = (lo2 + hi2) >> 1; if (batch[mid] < g + 1) lo2 = mid + 1; else hi2 = mid; }
  int cnt = lo2 - lo; if (cnt < 1) cnt = 1;
  float a0 = 0.f, a1 = 0.f;
#pragma unroll 4
  for (int s = 0; s < NSLOT; s++) {
    const float* row = gsum + ((size_t)g * NSLOT + s) * HID;
    a0 += row[l];
    a1 += row[64 + l];
  }
  float v = a0 * Wout[l] + a1 * Wout[64 + l];
#pragma unroll
  for (int s = 32; s >= 1; s >>= 1) v += __shfl_xor(v, s);
  if (l == 0) out[g] = v / (float)cnt + bout[0];
}

// ---------------------------------------------------------------------------
extern "C" void kernel_launch(void* const* d_in, const int* in_sizes, int n_in,
                              void* d_out, int out_size, void* d_ws, size_t ws_size,
                              hipStream_t stream) {
  const float* x         = (const float*)d_in[0];
  const float* edge_attr = (const float*)d_in[1];
  const float* Wq        = (const float*)d_in[2];
  const float* bq        = (const float*)d_in[3];
  const float* Wkv       = (const float*)d_in[4];
  const float* bkv       = (const float*)d_in[5];
  const float* Wdk       = (const float*)d_in[6];
  const float* bdk       = (const float*)d_in[7];
  const float* ln_in_g   = (const float*)d_in[8];
  const float* ln_in_b   = (const float*)d_in[9];
  const float* ln_out_g  = (const float*)d_in[10];
  const float* ln_out_b  = (const float*)d_in[11];
  const float* Wout      = (const float*)d_in[12];
  const float* bout      = (const float*)d_in[13];
  const int* edge_index  = (const int*)d_in[14];   // [2][E]: src then dst
  const int* batch       = (const int*)d_in[15];
  float* outp = (float*)d_out;

  char* ws = (char*)d_ws;
  float* qbuf          = (float*)ws;                                   // 25.6 MB
  unsigned short* kbuf = (unsigned short*)(ws + 25600000);             // 12.8 MB
  unsigned short* WBf  = (unsigned short*)(ws + 25600000 + 12800000);  // 64 KB
  unsigned short* Wdkf = (unsigned short*)(ws + 25600000 + 12800000 + 65536);
  float* gsum          = (float*)(ws + 25600000 + 12800000 + 65536 + 16384);  // 1 MB
  float* probescratch  = (float*)WBf;   // dead after node_kernel; 16K floats

  prep_kernel<<<32, 256, 0, stream>>>(Wq, Wkv, Wdk, WBf, Wdkf, gsum);
  node_kernel<<<(N_NODES + 63) / 64, 256, 0, stream>>>(x, bq, bkv, ln_in_g, ln_in_b,
                                                       WBf, qbuf, kbuf);
  edge_kernel<<<N_NODES / 4, 256, 0, stream>>>(x, edge_attr, edge_index, batch, bdk,
                                               ln_out_g, ln_out_b, qbuf, kbuf, Wdkf, gsum);
  readout_kernel<<<NG, 64, 0, stream>>>(gsum, batch, Wout, bout, outp);
  // --- ablation probes (dead scratch writes; informational only) -----------
  edge_probeA<<<N_NODES / 4, 256, 0, stream>>>(x, edge_attr, edge_index, batch,
                                               qbuf, kbuf, Wdkf, probescratch);
  edge_probeC<<<N_NODES / 4, 256, 0, stream>>>(x, edge_attr, edge_index, batch, bdk,
                                               ln_out_g, ln_out_b, qbuf, kbuf, Wdkf,
                                               probescratch);
}

// Round 7
// 144.805 us; speedup vs baseline: 2.1448x; 2.1448x over previous
//
#include <hip/hip_runtime.h>
#include <hip/hip_bf16.h>

#define N_NODES 50000
#define DEG 16
#define NE 800000
#define HID 128
#define NH 32
#define ECH 64
#define NG 64
#define NSLOT 32
#define LN_EPS 1e-5f

typedef __bf16 bf16x8 __attribute__((ext_vector_type(8)));
typedef float f32x4 __attribute__((ext_vector_type(4)));

__device__ __forceinline__ unsigned short f2bf(float f) {
  unsigned int u = __float_as_uint(f);
  u += 0x7FFFu + ((u >> 16) & 1u);          // round-to-nearest-even
  return (unsigned short)(u >> 16);
}
__device__ __forceinline__ unsigned int pack2(float a, float b) {
  return (unsigned int)f2bf(a) | ((unsigned int)f2bf(b) << 16);
}

// ---------------------------------------------------------------- prep ------
__global__ void prep_kernel(const float* __restrict__ Wq, const float* __restrict__ Wkv,
                            const float* __restrict__ Wdk,
                            unsigned short* __restrict__ WBf,
                            unsigned short* __restrict__ Wdkf,
                            float* __restrict__ gsum) {
  int b = blockIdx.x, t = threadIdx.x;
  if (b < 16) {
    int n = b;
    for (int idx = t; idx < 2048; idx += 256) {
      int j = idx & 7, l = (idx >> 3) & 63, kk = idx >> 9;
      int col = n * 16 + (l & 15);
      int k = kk * 32 + (l >> 4) * 8 + j;
      float v = (col < HID) ? Wq[k * HID + col] : Wkv[k * HID + (col - HID)];
      WBf[((n * 4 + kk) * 64 + l) * 8 + j] = f2bf(v);
    }
  } else if (b < 24) {
    int n2 = b - 16;
    for (int idx = t; idx < 1024; idx += 256) {
      int j = idx & 7, l = (idx >> 3) & 63, kk = idx >> 9;
      int col = n2 * 16 + (l & 15);
      int k = kk * 32 + (l >> 4) * 8 + j;
      Wdkf[((n2 * 2 + kk) * 64 + l) * 8 + j] = f2bf(Wdk[k * HID + col]);
    }
  } else {
    int chunk = b - 24;                      // 8 blocks zero NG*NSLOT*HID floats
    const int tot = NG * NSLOT * HID / 8;    // 32768 per block
    for (int i = chunk * tot + t; i < (chunk + 1) * tot; i += 256)
      gsum[i] = 0.0f;
  }
}

// ------------------------------------------------------------- node pass ----
__global__ __launch_bounds__(256) void node_kernel(
    const float* __restrict__ x, const float* __restrict__ bq,
    const float* __restrict__ bkv, const float* __restrict__ lng,
    const float* __restrict__ lnb, const unsigned short* __restrict__ WBf,
    float* __restrict__ qout, unsigned short* __restrict__ kout) {
  __shared__ __align__(16) unsigned short xn[64 * HID];
  int t = threadIdx.x;
  int node0 = blockIdx.x * 64;
  {
    int row = t >> 2, q4 = t & 3;
    int c0 = q4 * 32;
    int node = node0 + row;
    float v[32];
    if (node < N_NODES) {
      const float4* xp = (const float4*)(x + node * HID + c0);
#pragma unroll
      for (int i = 0; i < 8; i++) {
        float4 f = xp[i];
        v[4 * i] = f.x; v[4 * i + 1] = f.y; v[4 * i + 2] = f.z; v[4 * i + 3] = f.w;
      }
    } else {
#pragma unroll
      for (int i = 0; i < 32; i++) v[i] = 0.f;
    }
    float s = 0.f;
#pragma unroll
    for (int i = 0; i < 32; i++) s += v[i];
    s += __shfl_xor(s, 1); s += __shfl_xor(s, 2);
    float m = s * (1.0f / HID);
    float sq = 0.f;
#pragma unroll
    for (int i = 0; i < 32; i++) { float d = v[i] - m; sq += d * d; }
    sq += __shfl_xor(sq, 1); sq += __shfl_xor(sq, 2);
    float rstd = rsqrtf(sq * (1.0f / HID) + LN_EPS);
#pragma unroll
    for (int ch = 0; ch < 4; ch++) {
      float w0[8];
#pragma unroll
      for (int j = 0; j < 8; j++) {
        int c = c0 + ch * 8 + j;
        w0[j] = (v[ch * 8 + j] - m) * rstd * lng[c] + lnb[c];
      }
      uint4 u;
      u.x = pack2(w0[0], w0[1]); u.y = pack2(w0[2], w0[3]);
      u.z = pack2(w0[4], w0[5]); u.w = pack2(w0[6], w0[7]);
      int byte = row * 256 + ((c0 * 2 + ch * 16) ^ ((row & 7) << 4));
      *(uint4*)((char*)xn + byte) = u;
    }
  }
  __syncthreads();
  int w = t >> 6, l = t & 63;
  int arow = w * 16 + (l & 15);
  bf16x8 a[4];
#pragma unroll
  for (int kk = 0; kk < 4; kk++) {
    int byte = arow * 256 + ((kk * 64 + (l >> 4) * 16) ^ ((arow & 7) << 4));
    a[kk] = *(const bf16x8*)((const char*)xn + byte);
  }
  f32x4 acc[16];
#pragma unroll
  for (int n = 0; n < 16; n++) acc[n] = (f32x4){0.f, 0.f, 0.f, 0.f};
#pragma unroll
  for (int n = 0; n < 16; n++)
#pragma unroll
    for (int kk = 0; kk < 4; kk++) {
      bf16x8 bfr = *(const bf16x8*)(WBf + ((n * 4 + kk) * 64 + l) * 8);
      acc[n] = __builtin_amdgcn_mfma_f32_16x16x32_bf16(a[kk], bfr, acc[n], 0, 0, 0);
    }
#pragma unroll
  for (int n = 0; n < 16; n++) {
    int col = n * 16 + (l & 15);
    float bias = (col < HID) ? bq[col] : bkv[col - HID];
#pragma unroll
    for (int r = 0; r < 4; r++) {
      int node = node0 + w * 16 + (l >> 4) * 4 + r;
      if (node < N_NODES) {
        float vv = acc[n][r] + bias;
        if (col < HID) qout[node * HID + col] = vv;
        else kout[node * HID + (col - HID)] = f2bf(vv);
      }
    }
  }
}

// ------------------------------------------------------------- edge pass ----
// 4 nodes (64 edges) / block, 1 node / wave.
// Phase 1 (edge-major lanes): lane (el,eh) computes attention logits s and
//   at = silu(s) for edge el, heads n*4+eh via swapped-operand MFMA (dk) —
//   writes at to padded LDS at_s[node][edge][head].
// Phase 2 (channel-major lanes): lane l owns channels 2l,2l+1; accumulates
//   msg[c] = sum_e k[src[e]][c]*at[e][head(c)] with an in-register e-loop
//   (replaces 128 DPP adds/lane with 32 fma), then residual+LN (64-lane
//   reduce, no duplication) and the per-graph aggregation.
__global__ __launch_bounds__(256, 2) void edge_kernel(
    const float* __restrict__ x, const float* __restrict__ ea,
    const int* __restrict__ src_arr, const int* __restrict__ batch,
    const float* __restrict__ bdk, const float* __restrict__ lng,
    const float* __restrict__ lnb, const float* __restrict__ qg,
    const unsigned short* __restrict__ kbf,
    const unsigned short* __restrict__ Wdkf, float* __restrict__ gsum) {
  __shared__ __align__(16) unsigned short wdk_s[8 * 2 * 64 * 8];  // 16 KB
  __shared__ __align__(16) float xq_s[8 * HID];   // x rows | q rows
  __shared__ __align__(16) float prm_s[3 * HID];  // bdk | lng | lnb
  __shared__ __align__(16) float at_s[4 * 16 * 33]; // [node][edge][head] pad 33
  __shared__ __align__(16) float h_s[4 * 132];
  __shared__ int src_s[64];
  __shared__ int b4[4];
  int t = threadIdx.x;
  int node0 = blockIdx.x * 4;
  int w = t >> 6, l = t & 63, el = l & 15, eh = l >> 4;
  int ni = node0 + w;
  size_t e0n = (size_t)ni * DEG;

  // ---- stage broadcast operands (coalesced) -------------------------------
  xq_s[t]       = x[(size_t)node0 * HID + t];
  xq_s[256 + t] = x[(size_t)node0 * HID + 256 + t];
  xq_s[512 + t] = qg[(size_t)node0 * HID + t];
  xq_s[768 + t] = qg[(size_t)node0 * HID + 256 + t];
  if (t < HID) { prm_s[t] = bdk[t]; prm_s[HID + t] = lng[t]; prm_s[2 * HID + t] = lnb[t]; }
#pragma unroll
  for (int i = 0; i < 4; i++) {
    int idx = (i * 256 + t) * 8;
    *(uint4*)(wdk_s + idx) = *(const uint4*)(Wdkf + idx);
  }
  if (t < 64) src_s[t] = src_arr[(size_t)node0 * DEG + t];
  if (t < 4) b4[t] = batch[node0 + t];

  // ---- per-lane loads (edge-major) ----------------------------------------
  int srcn = src_arr[e0n + el];                       // 4-way broadcast
  const float* earow = ea + (e0n + el) * ECH + eh * 8;
  float4 ea00 = *(const float4*)(earow);
  float4 ea01 = *(const float4*)(earow + 4);
  float4 ea10 = *(const float4*)(earow + 32);
  float4 ea11 = *(const float4*)(earow + 36);
  const unsigned short* kr = kbf + (size_t)srcn * HID;
  uint2 kg[8];
#pragma unroll
  for (int n = 0; n < 8; n++) kg[n] = *(const uint2*)(kr + n * 16 + eh * 4);

  bf16x8 bfr[2];
  bfr[0][0] = (__bf16)ea00.x; bfr[0][1] = (__bf16)ea00.y;
  bfr[0][2] = (__bf16)ea00.z; bfr[0][3] = (__bf16)ea00.w;
  bfr[0][4] = (__bf16)ea01.x; bfr[0][5] = (__bf16)ea01.y;
  bfr[0][6] = (__bf16)ea01.z; bfr[0][7] = (__bf16)ea01.w;
  bfr[1][0] = (__bf16)ea10.x; bfr[1][1] = (__bf16)ea10.y;
  bfr[1][2] = (__bf16)ea10.z; bfr[1][3] = (__bf16)ea10.w;
  bfr[1][4] = (__bf16)ea11.x; bfr[1][5] = (__bf16)ea11.y;
  bfr[1][6] = (__bf16)ea11.z; bfr[1][7] = (__bf16)ea11.w;

  __syncthreads();                                    // wdk_s, src_s, xq_s ready

  // ---- channel-layout k gather (in flight under MFMA + n-loop) ------------
  unsigned int kw[16];
#pragma unroll
  for (int e = 0; e < 16; e++) {
    int sw = src_s[w * 16 + e];
    kw[e] = *(const unsigned int*)(kbf + (size_t)sw * HID + 2 * l);
  }

  // ---- dk^T = Wdk^T (A) x ea^T (B) ----------------------------------------
  f32x4 acc[8];
#pragma unroll
  for (int n = 0; n < 8; n++) acc[n] = (f32x4){0.f, 0.f, 0.f, 0.f};
#pragma unroll
  for (int n = 0; n < 8; n++)
#pragma unroll
    for (int kk = 0; kk < 2; kk++) {
      bf16x8 af = *(const bf16x8*)(wdk_s + ((n * 2 + kk) * 64 + l) * 8);
      acc[n] = __builtin_amdgcn_mfma_f32_16x16x32_bf16(af, bfr[kk], acc[n], 0, 0, 0);
    }

  // ---- attention logits + silu (edge-major) -------------------------------
#pragma unroll
  for (int n = 0; n < 8; n++) {
    const int cb = n * 16 + eh * 4;
    f32x4 qv = *(const f32x4*)&xq_s[512 + w * HID + cb];
    f32x4 bd = *(const f32x4*)&prm_s[cb];
    float k0 = __uint_as_float(kg[n].x << 16);
    float k1 = __uint_as_float(kg[n].x & 0xFFFF0000u);
    float k2 = __uint_as_float(kg[n].y << 16);
    float k3 = __uint_as_float(kg[n].y & 0xFFFF0000u);
    float d0 = acc[n][0] + bd[0];
    float d1 = acc[n][1] + bd[1];
    float d2 = acc[n][2] + bd[2];
    float d3 = acc[n][3] + bd[3];
    float s = qv[0] * k0 * d0 + qv[1] * k1 * d1 + qv[2] * k2 * d2 + qv[3] * k3 * d3;
    float at = s * __builtin_amdgcn_rcpf(1.0f + __expf(-s));   // silu
    at_s[w * 528 + el * 33 + n * 4 + eh] = at;       // same-wave write
  }

  // ---- message accumulation (channel-major, in-register over edges) -------
  // LDS write->read is same-wave (wave == node): DS pipe is in-order per
  // wave, compiler orders via aliasing; no block barrier needed here.
  int hl = l >> 1;                                    // head of channels 2l,2l+1
  float macc0 = 0.f, macc1 = 0.f;
#pragma unroll
  for (int e = 0; e < 16; e++) {
    float at = at_s[w * 528 + e * 33 + hl];
    float k0 = __uint_as_float(kw[e] << 16);
    float k1 = __uint_as_float(kw[e] & 0xFFFF0000u);
    macc0 = fmaf(k0, at, macc0);
    macc1 = fmaf(k1, at, macc1);
  }
  float2 xv = *(const float2*)&xq_s[w * HID + 2 * l];
  float h10 = xv.x + macc0 * 0.0625f;
  float h11 = xv.y + macc1 * 0.0625f;
  // ---- LayerNorm (64-lane reduce, 2 ch/lane) ------------------------------
  float ss = h10 + h11;
  ss += __shfl_xor(ss, 1);  ss += __shfl_xor(ss, 2);  ss += __shfl_xor(ss, 4);
  ss += __shfl_xor(ss, 8);  ss += __shfl_xor(ss, 16); ss += __shfl_xor(ss, 32);
  float mean = ss * (1.0f / HID);
  float dv0 = h10 - mean, dv1 = h11 - mean;
  float vv = dv0 * dv0 + dv1 * dv1;
  vv += __shfl_xor(vv, 1);  vv += __shfl_xor(vv, 2);  vv += __shfl_xor(vv, 4);
  vv += __shfl_xor(vv, 8);  vv += __shfl_xor(vv, 16); vv += __shfl_xor(vv, 32);
  float rstd = rsqrtf(vv * (1.0f / HID) + LN_EPS);
  float2 gv = *(const float2*)&prm_s[HID + 2 * l];
  float2 bv = *(const float2*)&prm_s[2 * HID + 2 * l];
  float2 ho;
  ho.x = xv.x + dv0 * rstd * gv.x + bv.x;
  ho.y = xv.y + dv1 * rstd * gv.y + bv.y;
  *(float2*)&h_s[w * 132 + 2 * l] = ho;
  __syncthreads();
  if (t < HID) {                         // run-length-compress by graph
    int c = t;
    int slot = blockIdx.x & (NSLOT - 1);
    float accu = h_s[c];
#pragma unroll
    for (int nn = 1; nn < 4; nn++) {
      if (b4[nn] == b4[nn - 1]) accu += h_s[nn * 132 + c];
      else {
        atomicAdd(&gsum[(b4[nn - 1] * NSLOT + slot) * HID + c], accu);
        accu = h_s[nn * 132 + c];
      }
    }
    atomicAdd(&gsum[(b4[3] * NSLOT + slot) * HID + c], accu);
  }
}

// -------------------------------------------------------------- readout -----
__global__ void readout_kernel(const float* __restrict__ gsum,
                               const int* __restrict__ batch,
                               const float* __restrict__ Wout,
                               const float* __restrict__ bout,
                               float* __restrict__ out) {
  int g = blockIdx.x, l = threadIdx.x;
  int lo = 0, hi = N_NODES;
  while (lo < hi) { int mid = (lo + hi) >> 1; if (batch[mid] < g) lo = mid + 1; else hi = mid; }
  int lo2 = lo, hi2 = N_NODES;
  while (lo2 < hi2) { int mid = (lo2 + hi2) >> 1; if (batch[mid] < g + 1) lo2 = mid + 1; else hi2 = mid; }
  int cnt = lo2 - lo; if (cnt < 1) cnt = 1;
  float a0 = 0.f, a1 = 0.f;
#pragma unroll 4
  for (int s = 0; s < NSLOT; s++) {
    const float* row = gsum + ((size_t)g * NSLOT + s) * HID;
    a0 += row[l];
    a1 += row[64 + l];
  }
  float v = a0 * Wout[l] + a1 * Wout[64 + l];
#pragma unroll
  for (int s = 32; s >= 1; s >>= 1) v += __shfl_xor(v, s);
  if (l == 0) out[g] = v / (float)cnt + bout[0];
}

// ---------------------------------------------------------------------------
extern "C" void kernel_launch(void* const* d_in, const int* in_sizes, int n_in,
                              void* d_out, int out_size, void* d_ws, size_t ws_size,
                              hipStream_t stream) {
  const float* x         = (const float*)d_in[0];
  const float* edge_attr = (const float*)d_in[1];
  const float* Wq        = (const float*)d_in[2];
  const float* bq        = (const float*)d_in[3];
  const float* Wkv       = (const float*)d_in[4];
  const float* bkv       = (const float*)d_in[5];
  const float* Wdk       = (const float*)d_in[6];
  const float* bdk       = (const float*)d_in[7];
  const float* ln_in_g   = (const float*)d_in[8];
  const float* ln_in_b   = (const float*)d_in[9];
  const float* ln_out_g  = (const float*)d_in[10];
  const float* ln_out_b  = (const float*)d_in[11];
  const float* Wout      = (const float*)d_in[12];
  const float* bout      = (const float*)d_in[13];
  const int* edge_index  = (const int*)d_in[14];   // [2][E]: src then dst
  const int* batch       = (const int*)d_in[15];
  float* outp = (float*)d_out;

  char* ws = (char*)d_ws;
  float* qbuf          = (float*)ws;                                   // 25.6 MB
  unsigned short* kbuf = (unsigned short*)(ws + 25600000);             // 12.8 MB
  unsigned short* WBf  = (unsigned short*)(ws + 25600000 + 12800000);  // 64 KB
  unsigned short* Wdkf = (unsigned short*)(ws + 25600000 + 12800000 + 65536);
  float* gsum          = (float*)(ws + 25600000 + 12800000 + 65536 + 16384);  // 1 MB

  prep_kernel<<<32, 256, 0, stream>>>(Wq, Wkv, Wdk, WBf, Wdkf, gsum);
  node_kernel<<<(N_NODES + 63) / 64, 256, 0, stream>>>(x, bq, bkv, ln_in_g, ln_in_b,
                                                       WBf, qbuf, kbuf);
  edge_kernel<<<N_NODES / 4, 256, 0, stream>>>(x, edge_attr, edge_index, batch, bdk,
                                               ln_out_g, ln_out_b, qbuf, kbuf, Wdkf, gsum);
  readout_kernel<<<NG, 64, 0, stream>>>(gsum, batch, Wout, bout, outp);
}

// Round 9
// 135.322 us; speedup vs baseline: 2.2951x; 1.0701x over previous
//
#include <hip/hip_runtime.h>
#include <hip/hip_bf16.h>

#define N_NODES 50000
#define DEG 16
#define NE 800000
#define HID 128
#define NH 32
#define ECH 64
#define NG 64
#define NSLOT 32
#define LN_EPS 1e-5f

typedef __bf16 bf16x8 __attribute__((ext_vector_type(8)));
typedef float f32x4 __attribute__((ext_vector_type(4)));

__device__ __forceinline__ unsigned short f2bf(float f) {
  unsigned int u = __float_as_uint(f);
  u += 0x7FFFu + ((u >> 16) & 1u);          // round-to-nearest-even
  return (unsigned short)(u >> 16);
}
__device__ __forceinline__ unsigned int pack2(float a, float b) {
  return (unsigned int)f2bf(a) | ((unsigned int)f2bf(b) << 16);
}

// ---------------------------------------------------------------- prep ------
__global__ void prep_kernel(const float* __restrict__ Wq, const float* __restrict__ Wkv,
                            const float* __restrict__ Wdk,
                            unsigned short* __restrict__ WBf,
                            unsigned short* __restrict__ Wdkf,
                            float* __restrict__ gsum) {
  int b = blockIdx.x, t = threadIdx.x;
  if (b < 16) {
    int n = b;
    for (int idx = t; idx < 2048; idx += 256) {
      int j = idx & 7, l = (idx >> 3) & 63, kk = idx >> 9;
      int col = n * 16 + (l & 15);
      int k = kk * 32 + (l >> 4) * 8 + j;
      float v = (col < HID) ? Wq[k * HID + col] : Wkv[k * HID + (col - HID)];
      WBf[((n * 4 + kk) * 64 + l) * 8 + j] = f2bf(v);
    }
  } else if (b < 24) {
    int n2 = b - 16;
    for (int idx = t; idx < 1024; idx += 256) {
      int j = idx & 7, l = (idx >> 3) & 63, kk = idx >> 9;
      int col = n2 * 16 + (l & 15);
      int k = kk * 32 + (l >> 4) * 8 + j;
      Wdkf[((n2 * 2 + kk) * 64 + l) * 8 + j] = f2bf(Wdk[k * HID + col]);
    }
  } else {
    int chunk = b - 24;                      // 8 blocks zero NG*NSLOT*HID floats
    const int tot = NG * NSLOT * HID / 8;    // 32768 per block
    for (int i = chunk * tot + t; i < (chunk + 1) * tot; i += 256)
      gsum[i] = 0.0f;
  }
}

// ------------------------------------------------------------- node pass ----
__global__ __launch_bounds__(256) void node_kernel(
    const float* __restrict__ x, const float* __restrict__ bq,
    const float* __restrict__ bkv, const float* __restrict__ lng,
    const float* __restrict__ lnb, const unsigned short* __restrict__ WBf,
    float* __restrict__ qout, unsigned short* __restrict__ kout) {
  __shared__ __align__(16) unsigned short xn[64 * HID];
  int t = threadIdx.x;
  int node0 = blockIdx.x * 64;
  {
    int row = t >> 2, q4 = t & 3;
    int c0 = q4 * 32;
    int node = node0 + row;
    float v[32];
    if (node < N_NODES) {
      const float4* xp = (const float4*)(x + node * HID + c0);
#pragma unroll
      for (int i = 0; i < 8; i++) {
        float4 f = xp[i];
        v[4 * i] = f.x; v[4 * i + 1] = f.y; v[4 * i + 2] = f.z; v[4 * i + 3] = f.w;
      }
    } else {
#pragma unroll
      for (int i = 0; i < 32; i++) v[i] = 0.f;
    }
    float s = 0.f;
#pragma unroll
    for (int i = 0; i < 32; i++) s += v[i];
    s += __shfl_xor(s, 1); s += __shfl_xor(s, 2);
    float m = s * (1.0f / HID);
    float sq = 0.f;
#pragma unroll
    for (int i = 0; i < 32; i++) { float d = v[i] - m; sq += d * d; }
    sq += __shfl_xor(sq, 1); sq += __shfl_xor(sq, 2);
    float rstd = rsqrtf(sq * (1.0f / HID) + LN_EPS);
#pragma unroll
    for (int ch = 0; ch < 4; ch++) {
      float w0[8];
#pragma unroll
      for (int j = 0; j < 8; j++) {
        int c = c0 + ch * 8 + j;
        w0[j] = (v[ch * 8 + j] - m) * rstd * lng[c] + lnb[c];
      }
      uint4 u;
      u.x = pack2(w0[0], w0[1]); u.y = pack2(w0[2], w0[3]);
      u.z = pack2(w0[4], w0[5]); u.w = pack2(w0[6], w0[7]);
      int byte = row * 256 + ((c0 * 2 + ch * 16) ^ ((row & 7) << 4));
      *(uint4*)((char*)xn + byte) = u;
    }
  }
  __syncthreads();
  int w = t >> 6, l = t & 63;
  int arow = w * 16 + (l & 15);
  bf16x8 a[4];
#pragma unroll
  for (int kk = 0; kk < 4; kk++) {
    int byte = arow * 256 + ((kk * 64 + (l >> 4) * 16) ^ ((arow & 7) << 4));
    a[kk] = *(const bf16x8*)((const char*)xn + byte);
  }
  f32x4 acc[16];
#pragma unroll
  for (int n = 0; n < 16; n++) acc[n] = (f32x4){0.f, 0.f, 0.f, 0.f};
#pragma unroll
  for (int n = 0; n < 16; n++)
#pragma unroll
    for (int kk = 0; kk < 4; kk++) {
      bf16x8 bfr = *(const bf16x8*)(WBf + ((n * 4 + kk) * 64 + l) * 8);
      acc[n] = __builtin_amdgcn_mfma_f32_16x16x32_bf16(a[kk], bfr, acc[n], 0, 0, 0);
    }
#pragma unroll
  for (int n = 0; n < 16; n++) {
    int col = n * 16 + (l & 15);
    float bias = (col < HID) ? bq[col] : bkv[col - HID];
#pragma unroll
    for (int r = 0; r < 4; r++) {
      int node = node0 + w * 16 + (l >> 4) * 4 + r;
      if (node < N_NODES) {
        float vv = acc[n][r] + bias;
        if (col < HID) qout[node * HID + col] = vv;
        else kout[node * HID + (col - HID)] = f2bf(vv);
      }
    }
  }
}

// ------------------------------------------------------------- edge pass ----
// 4 nodes (64 edges) / block, 1 node / wave.
// k path: ONE coalesced channel-major gather (kw, 16 x 256B rows) feeds both
//   phases — kw stays in registers for phase 2 and is staged into wave-private
//   swizzled LDS (k_s) for phase 1's fragment reads. The old edge-major
//   scattered gather (8 instr x 16 lines each) is gone.
// Wdk fragments are read directly from global (16 KB, L1-resident across all
//   blocks on the CU); ea loads are nontemporal to protect L1.
__global__ __launch_bounds__(256, 4) void edge_kernel(
    const float* __restrict__ x, const float* __restrict__ ea,
    const int* __restrict__ src_arr, const int* __restrict__ batch,
    const float* __restrict__ bdk, const float* __restrict__ lng,
    const float* __restrict__ lnb, const float* __restrict__ qg,
    const unsigned short* __restrict__ kbf,
    const unsigned short* __restrict__ Wdkf, float* __restrict__ gsum) {
  __shared__ __align__(16) float xq_s[8 * HID];          // x rows | q rows (4 KB)
  __shared__ __align__(16) float prm_s[3 * HID];         // bdk | lng | lnb
  __shared__ __align__(16) float at_s[4 * 16 * 33];      // [node][edge][head]
  __shared__ __align__(16) float h_s[4 * 132];
  __shared__ __align__(16) unsigned short k_s[4 * 16 * HID];  // 16 KB swizzled
  __shared__ int src_s[64];
  __shared__ int b4[4];
  int t = threadIdx.x;
  int node0 = blockIdx.x * 4;
  int w = t >> 6, l = t & 63, el = l & 15, eh = l >> 4;
  size_t e0n = (size_t)(node0 + w) * DEG;

  // ---- stage broadcast operands (coalesced) -------------------------------
  xq_s[t]       = x[(size_t)node0 * HID + t];
  xq_s[256 + t] = x[(size_t)node0 * HID + 256 + t];
  xq_s[512 + t] = qg[(size_t)node0 * HID + t];
  xq_s[768 + t] = qg[(size_t)node0 * HID + 256 + t];
  if (t < HID) { prm_s[t] = bdk[t]; prm_s[HID + t] = lng[t]; prm_s[2 * HID + t] = lnb[t]; }
  if (t < 64) src_s[t] = src_arr[(size_t)node0 * DEG + t];
  if (t < 4) b4[t] = batch[node0 + t];

  // ---- per-lane ea loads (streaming, nontemporal) -------------------------
  const float* earow = ea + (e0n + el) * ECH + eh * 8;
  f32x4 ea00 = __builtin_nontemporal_load((const f32x4*)(earow));
  f32x4 ea01 = __builtin_nontemporal_load((const f32x4*)(earow + 4));
  f32x4 ea10 = __builtin_nontemporal_load((const f32x4*)(earow + 32));
  f32x4 ea11 = __builtin_nontemporal_load((const f32x4*)(earow + 36));

  bf16x8 bfr[2];
  bfr[0][0] = (__bf16)ea00[0]; bfr[0][1] = (__bf16)ea00[1];
  bfr[0][2] = (__bf16)ea00[2]; bfr[0][3] = (__bf16)ea00[3];
  bfr[0][4] = (__bf16)ea01[0]; bfr[0][5] = (__bf16)ea01[1];
  bfr[0][6] = (__bf16)ea01[2]; bfr[0][7] = (__bf16)ea01[3];
  bfr[1][0] = (__bf16)ea10[0]; bfr[1][1] = (__bf16)ea10[1];
  bfr[1][2] = (__bf16)ea10[2]; bfr[1][3] = (__bf16)ea10[3];
  bfr[1][4] = (__bf16)ea11[0]; bfr[1][5] = (__bf16)ea11[1];
  bfr[1][6] = (__bf16)ea11[2]; bfr[1][7] = (__bf16)ea11[3];

  __syncthreads();                                    // src_s, xq_s, prm_s ready

  // ---- channel-major k gather (coalesced 256B rows) -----------------------
  unsigned int kw[16];
#pragma unroll
  for (int e = 0; e < 16; e++) {
    int sw = src_s[w * 16 + e];
    kw[e] = *(const unsigned int*)(kbf + (size_t)sw * HID + 2 * l);
  }
  // stage into wave-private swizzled LDS for phase-1 fragment reads
  char* kswW = (char*)k_s + w * 4096;
#pragma unroll
  for (int e = 0; e < 16; e++)
    *(unsigned int*)(kswW + e * 256 + ((4 * l) ^ ((e & 7) << 4))) = kw[e];

  // ---- dk^T = Wdk^T (A, global/L1) x ea^T (B) -----------------------------
  f32x4 acc[8];
#pragma unroll
  for (int n = 0; n < 8; n++) acc[n] = (f32x4){0.f, 0.f, 0.f, 0.f};
#pragma unroll
  for (int n = 0; n < 8; n++)
#pragma unroll
    for (int kk = 0; kk < 2; kk++) {
      bf16x8 af = *(const bf16x8*)(Wdkf + ((n * 2 + kk) * 64 + l) * 8);
      acc[n] = __builtin_amdgcn_mfma_f32_16x16x32_bf16(af, bfr[kk], acc[n], 0, 0, 0);
    }

  // ---- attention logits + silu (edge-major; k fragments from k_s) ---------
  const char* kswR = (const char*)k_s + w * 4096;
#pragma unroll
  for (int n = 0; n < 8; n++) {
    const int cb = n * 16 + eh * 4;
    f32x4 qv = *(const f32x4*)&xq_s[512 + w * HID + cb];
    f32x4 bd = *(const f32x4*)&prm_s[cb];
    uint2 kk2 = *(const uint2*)(kswR + el * 256 + ((n * 32 + eh * 8) ^ ((el & 7) << 4)));
    float k0 = __uint_as_float(kk2.x << 16);
    float k1 = __uint_as_float(kk2.x & 0xFFFF0000u);
    float k2 = __uint_as_float(kk2.y << 16);
    float k3 = __uint_as_float(kk2.y & 0xFFFF0000u);
    float d0 = acc[n][0] + bd[0];
    float d1 = acc[n][1] + bd[1];
    float d2 = acc[n][2] + bd[2];
    float d3 = acc[n][3] + bd[3];
    float s = qv[0] * k0 * d0 + qv[1] * k1 * d1 + qv[2] * k2 * d2 + qv[3] * k3 * d3;
    float at = s * __builtin_amdgcn_rcpf(1.0f + __expf(-s));   // silu
    at_s[w * 528 + el * 33 + n * 4 + eh] = at;       // same-wave write
  }

  // ---- message accumulation (channel-major, kw in registers) --------------
  int hl = l >> 1;                                    // head of channels 2l,2l+1
  float macc0 = 0.f, macc1 = 0.f;
#pragma unroll
  for (int e = 0; e < 16; e++) {
    float at = at_s[w * 528 + e * 33 + hl];
    float k0 = __uint_as_float(kw[e] << 16);
    float k1 = __uint_as_float(kw[e] & 0xFFFF0000u);
    macc0 = fmaf(k0, at, macc0);
    macc1 = fmaf(k1, at, macc1);
  }
  float2 xv = *(const float2*)&xq_s[w * HID + 2 * l];
  float h10 = xv.x + macc0 * 0.0625f;
  float h11 = xv.y + macc1 * 0.0625f;
  // ---- LayerNorm (64-lane reduce, 2 ch/lane) ------------------------------
  float ss = h10 + h11;
  ss += __shfl_xor(ss, 1);  ss += __shfl_xor(ss, 2);  ss += __shfl_xor(ss, 4);
  ss += __shfl_xor(ss, 8);  ss += __shfl_xor(ss, 16); ss += __shfl_xor(ss, 32);
  float mean = ss * (1.0f / HID);
  float dv0 = h10 - mean, dv1 = h11 - mean;
  float vv = dv0 * dv0 + dv1 * dv1;
  vv += __shfl_xor(vv, 1);  vv += __shfl_xor(vv, 2);  vv += __shfl_xor(vv, 4);
  vv += __shfl_xor(vv, 8);  vv += __shfl_xor(vv, 16); vv += __shfl_xor(vv, 32);
  float rstd = rsqrtf(vv * (1.0f / HID) + LN_EPS);
  float2 gv = *(const float2*)&prm_s[HID + 2 * l];
  float2 bv = *(const float2*)&prm_s[2 * HID + 2 * l];
  float2 ho;
  ho.x = xv.x + dv0 * rstd * gv.x + bv.x;
  ho.y = xv.y + dv1 * rstd * gv.y + bv.y;
  *(float2*)&h_s[w * 132 + 2 * l] = ho;
  __syncthreads();
  if (t < HID) {                         // run-length-compress by graph
    int c = t;
    int slot = blockIdx.x & (NSLOT - 1);
    float accu = h_s[c];
#pragma unroll
    for (int nn = 1; nn < 4; nn++) {
      if (b4[nn] == b4[nn - 1]) accu += h_s[nn * 132 + c];
      else {
        atomicAdd(&gsum[(b4[nn - 1] * NSLOT + slot) * HID + c], accu);
        accu = h_s[nn * 132 + c];
      }
    }
    atomicAdd(&gsum[(b4[3] * NSLOT + slot) * HID + c], accu);
  }
}

// -------------------------------------------------------------- readout -----
__global__ void readout_kernel(const float* __restrict__ gsum,
                               const int* __restrict__ batch,
                               const float* __restrict__ Wout,
                               const float* __restrict__ bout,
                               float* __restrict__ out) {
  int g = blockIdx.x, l = threadIdx.x;
  int lo = 0, hi = N_NODES;
  while (lo < hi) { int mid = (lo + hi) >> 1; if (batch[mid] < g) lo = mid + 1; else hi = mid; }
  int lo2 = lo, hi2 = N_NODES;
  while (lo2 < hi2) { int mid = (lo2 + hi2) >> 1; if (batch[mid] < g + 1) lo2 = mid + 1; else hi2 = mid; }
  int cnt = lo2 - lo; if (cnt < 1) cnt = 1;
  float a0 = 0.f, a1 = 0.f;
#pragma unroll 4
  for (int s = 0; s < NSLOT; s++) {
    const float* row = gsum + ((size_t)g * NSLOT + s) * HID;
    a0 += row[l];
    a1 += row[64 + l];
  }
  float v = a0 * Wout[l] + a1 * Wout[64 + l];
#pragma unroll
  for (int s = 32; s >= 1; s >>= 1) v += __shfl_xor(v, s);
  if (l == 0) out[g] = v / (float)cnt + bout[0];
}

// ---------------------------------------------------------------------------
extern "C" void kernel_launch(void* const* d_in, const int* in_sizes, int n_in,
                              void* d_out, int out_size, void* d_ws, size_t ws_size,
                              hipStream_t stream) {
  const float* x         = (const float*)d_in[0];
  const float* edge_attr = (const float*)d_in[1];
  const float* Wq        = (const float*)d_in[2];
  const float* bq        = (const float*)d_in[3];
  const float* Wkv       = (const float*)d_in[4];
  const float* bkv       = (const float*)d_in[5];
  const float* Wdk       = (const float*)d_in[6];
  const float* bdk       = (const float*)d_in[7];
  const float* ln_in_g   = (const float*)d_in[8];
  const float* ln_in_b   = (const float*)d_in[9];
  const float* ln_out_g  = (const float*)d_in[10];
  const float* ln_out_b  = (const float*)d_in[11];
  const float* Wout      = (const float*)d_in[12];
  const float* bout      = (const float*)d_in[13];
  const int* edge_index  = (const int*)d_in[14];   // [2][E]: src then dst
  const int* batch       = (const int*)d_in[15];
  float* outp = (float*)d_out;

  char* ws = (char*)d_ws;
  float* qbuf          = (float*)ws;                                   // 25.6 MB
  unsigned short* kbuf = (unsigned short*)(ws + 25600000);             // 12.8 MB
  unsigned short* WBf  = (unsigned short*)(ws + 25600000 + 12800000);  // 64 KB
  unsigned short* Wdkf = (unsigned short*)(ws + 25600000 + 12800000 + 65536);
  float* gsum          = (float*)(ws + 25600000 + 12800000 + 65536 + 16384);  // 1 MB

  prep_kernel<<<32, 256, 0, stream>>>(Wq, Wkv, Wdk, WBf, Wdkf, gsum);
  node_kernel<<<(N_NODES + 63) / 64, 256, 0, stream>>>(x, bq, bkv, ln_in_g, ln_in_b,
                                                       WBf, qbuf, kbuf);
  edge_kernel<<<N_NODES / 4, 256, 0, stream>>>(x, edge_attr, edge_index, batch, bdk,
                                               ln_out_g, ln_out_b, qbuf, kbuf, Wdkf, gsum);
  readout_kernel<<<NG, 64, 0, stream>>>(gsum, batch, Wout, bout, outp);
}

// Round 10
// 126.375 us; speedup vs baseline: 2.4576x; 1.0708x over previous
//
#include <hip/hip_runtime.h>
#include <hip/hip_bf16.h>

#define N_NODES 50000
#define DEG 16
#define NE 800000
#define HID 128
#define NH 32
#define ECH 64
#define NG 64
#define NSLOT 32
#define ITER 5
#define LN_EPS 1e-5f

typedef __bf16 bf16x8 __attribute__((ext_vector_type(8)));
typedef float f32x4 __attribute__((ext_vector_type(4)));

__device__ __forceinline__ unsigned short f2bf(float f) {
  unsigned int u = __float_as_uint(f);
  u += 0x7FFFu + ((u >> 16) & 1u);          // round-to-nearest-even
  return (unsigned short)(u >> 16);
}
__device__ __forceinline__ unsigned int pack2(float a, float b) {
  return (unsigned int)f2bf(a) | ((unsigned int)f2bf(b) << 16);
}

// ---------------------------------------------------------------- prep ------
__global__ void prep_kernel(const float* __restrict__ Wq, const float* __restrict__ Wkv,
                            const float* __restrict__ Wdk,
                            unsigned short* __restrict__ WBf,
                            unsigned short* __restrict__ Wdkf,
                            float* __restrict__ gsum) {
  int b = blockIdx.x, t = threadIdx.x;
  if (b < 16) {
    int n = b;
    for (int idx = t; idx < 2048; idx += 256) {
      int j = idx & 7, l = (idx >> 3) & 63, kk = idx >> 9;
      int col = n * 16 + (l & 15);
      int k = kk * 32 + (l >> 4) * 8 + j;
      float v = (col < HID) ? Wq[k * HID + col] : Wkv[k * HID + (col - HID)];
      WBf[((n * 4 + kk) * 64 + l) * 8 + j] = f2bf(v);
    }
  } else if (b < 24) {
    int n2 = b - 16;
    for (int idx = t; idx < 1024; idx += 256) {
      int j = idx & 7, l = (idx >> 3) & 63, kk = idx >> 9;
      int col = n2 * 16 + (l & 15);
      int k = kk * 32 + (l >> 4) * 8 + j;
      Wdkf[((n2 * 2 + kk) * 64 + l) * 8 + j] = f2bf(Wdk[k * HID + col]);
    }
  } else {
    int chunk = b - 24;                      // 8 blocks zero NG*NSLOT*HID floats
    const int tot = NG * NSLOT * HID / 8;    // 32768 per block
    for (int i = chunk * tot + t; i < (chunk + 1) * tot; i += 256)
      gsum[i] = 0.0f;
  }
}

// ------------------------------------------------------------- node pass ----
__global__ __launch_bounds__(256) void node_kernel(
    const float* __restrict__ x, const float* __restrict__ bq,
    const float* __restrict__ bkv, const float* __restrict__ lng,
    const float* __restrict__ lnb, const unsigned short* __restrict__ WBf,
    float* __restrict__ qout, unsigned short* __restrict__ kout) {
  __shared__ __align__(16) unsigned short xn[64 * HID];
  int t = threadIdx.x;
  int node0 = blockIdx.x * 64;
  {
    int row = t >> 2, q4 = t & 3;
    int c0 = q4 * 32;
    int node = node0 + row;
    float v[32];
    if (node < N_NODES) {
      const float4* xp = (const float4*)(x + node * HID + c0);
#pragma unroll
      for (int i = 0; i < 8; i++) {
        float4 f = xp[i];
        v[4 * i] = f.x; v[4 * i + 1] = f.y; v[4 * i + 2] = f.z; v[4 * i + 3] = f.w;
      }
    } else {
#pragma unroll
      for (int i = 0; i < 32; i++) v[i] = 0.f;
    }
    float s = 0.f;
#pragma unroll
    for (int i = 0; i < 32; i++) s += v[i];
    s += __shfl_xor(s, 1); s += __shfl_xor(s, 2);
    float m = s * (1.0f / HID);
    float sq = 0.f;
#pragma unroll
    for (int i = 0; i < 32; i++) { float d = v[i] - m; sq += d * d; }
    sq += __shfl_xor(sq, 1); sq += __shfl_xor(sq, 2);
    float rstd = rsqrtf(sq * (1.0f / HID) + LN_EPS);
#pragma unroll
    for (int ch = 0; ch < 4; ch++) {
      float w0[8];
#pragma unroll
      for (int j = 0; j < 8; j++) {
        int c = c0 + ch * 8 + j;
        w0[j] = (v[ch * 8 + j] - m) * rstd * lng[c] + lnb[c];
      }
      uint4 u;
      u.x = pack2(w0[0], w0[1]); u.y = pack2(w0[2], w0[3]);
      u.z = pack2(w0[4], w0[5]); u.w = pack2(w0[6], w0[7]);
      int byte = row * 256 + ((c0 * 2 + ch * 16) ^ ((row & 7) << 4));
      *(uint4*)((char*)xn + byte) = u;
    }
  }
  __syncthreads();
  int w = t >> 6, l = t & 63;
  int arow = w * 16 + (l & 15);
  bf16x8 a[4];
#pragma unroll
  for (int kk = 0; kk < 4; kk++) {
    int byte = arow * 256 + ((kk * 64 + (l >> 4) * 16) ^ ((arow & 7) << 4));
    a[kk] = *(const bf16x8*)((const char*)xn + byte);
  }
  f32x4 acc[16];
#pragma unroll
  for (int n = 0; n < 16; n++) acc[n] = (f32x4){0.f, 0.f, 0.f, 0.f};
#pragma unroll
  for (int n = 0; n < 16; n++)
#pragma unroll
    for (int kk = 0; kk < 4; kk++) {
      bf16x8 bfr = *(const bf16x8*)(WBf + ((n * 4 + kk) * 64 + l) * 8);
      acc[n] = __builtin_amdgcn_mfma_f32_16x16x32_bf16(a[kk], bfr, acc[n], 0, 0, 0);
    }
#pragma unroll
  for (int n = 0; n < 16; n++) {
    int col = n * 16 + (l & 15);
    float bias = (col < HID) ? bq[col] : bkv[col - HID];
#pragma unroll
    for (int r = 0; r < 4; r++) {
      int node = node0 + w * 16 + (l >> 4) * 4 + r;
      if (node < N_NODES) {
        float vv = acc[n][r] + bias;
        if (col < HID) qout[node * HID + col] = vv;
        else kout[node * HID + (col - HID)] = f2bf(vv);
      }
    }
  }
}

// ------------------------------------------------------------- edge pass ----
// Persistent blocks: each processes ITER=5 consecutive 4-node groups with a
// software pipeline — all group-(i+1) loads (src two-deep, ea, x/q, batch,
// k-gather) are issued during group i's compute into ping-pong register
// slots (full unroll -> compile-time indices). Aggregation run-length
// compresses across all 5 groups in registers (one atomic per graph-run per
// block). src is broadcast via __shfl(.,e,16) — no LDS round trip.
__global__ __launch_bounds__(256, 2) void edge_kernel(
    const float* __restrict__ x, const float* __restrict__ ea,
    const int* __restrict__ src_arr, const int* __restrict__ batch,
    const float* __restrict__ bdk, const float* __restrict__ lng,
    const float* __restrict__ lnb, const float* __restrict__ qg,
    const unsigned short* __restrict__ kbf,
    const unsigned short* __restrict__ Wdkf, float* __restrict__ gsum) {
  __shared__ __align__(16) unsigned short wdk_s[8 * 2 * 64 * 8];  // 16 KB
  __shared__ __align__(16) float xq_s[8 * HID];                   // 4 KB
  __shared__ __align__(16) float prm_s[3 * HID];
  __shared__ __align__(16) float at_s[4 * 16 * 33];               // 8.4 KB
  __shared__ __align__(16) float h_s[4 * 132];
  __shared__ __align__(16) unsigned short k_s[4 * 16 * HID];      // 16 KB
  __shared__ int b4_s[2][4];
  int t = threadIdx.x;
  int w = t >> 6, l = t & 63, el = l & 15, eh = l >> 4;
  int g0 = blockIdx.x * ITER;

  if (t < HID) { prm_s[t] = bdk[t]; prm_s[HID + t] = lng[t]; prm_s[2 * HID + t] = lnb[t]; }
#pragma unroll
  for (int i = 0; i < 4; i++) {
    int idx = (i * 256 + t) * 8;
    *(uint4*)(wdk_s + idx) = *(const uint4*)(Wdkf + idx);
  }

  // aggregation state (t<128 meaningful)
  int slot = blockIdx.x & (NSLOT - 1);
  int curG = batch[g0 * 4];
  float accu = 0.f;

  // ping-pong register slots
  unsigned int kwR[2][16];
  f32x4 eaR[2][4];
  float xqR[2][4];
  int srcR[2], b4R[2];

  auto LOAD_SRC = [&](int g) -> int {
    return src_arr[(size_t)g * 64 + w * 16 + el];
  };
  auto LOAD_GROUP = [&](int g, int s) {
    size_t node0 = (size_t)g * 4;
    const float* earow = ea + ((node0 + w) * DEG + el) * ECH + eh * 8;
    eaR[s][0] = __builtin_nontemporal_load((const f32x4*)(earow));
    eaR[s][1] = __builtin_nontemporal_load((const f32x4*)(earow + 4));
    eaR[s][2] = __builtin_nontemporal_load((const f32x4*)(earow + 32));
    eaR[s][3] = __builtin_nontemporal_load((const f32x4*)(earow + 36));
    xqR[s][0] = x[node0 * HID + t];
    xqR[s][1] = x[node0 * HID + 256 + t];
    xqR[s][2] = qg[node0 * HID + t];
    xqR[s][3] = qg[node0 * HID + 256 + t];
    b4R[s] = batch[node0 + (t & 3)];
  };
  auto GATHER = [&](int s) {
    int sv = srcR[s];
#pragma unroll
    for (int e = 0; e < 16; e++) {
      int sw = __shfl(sv, e, 16);
      kwR[s][e] = *(const unsigned int*)(kbf + (size_t)sw * HID + 2 * l);
    }
  };

  // prologue
  srcR[0] = LOAD_SRC(g0);
  LOAD_GROUP(g0, 0);
  srcR[1] = LOAD_SRC(g0 + 1);
  GATHER(0);

#pragma unroll
  for (int i = 0; i < ITER; i++) {
    const int cur = i & 1, nxt = cur ^ 1;
    // ---- (A) issue next-group memory ops ----------------------------------
    if (i + 1 < ITER) GATHER(nxt);                 // kw for i+1 (src arrived)
    if (i + 2 < ITER) srcR[cur] = LOAD_SRC(g0 + i + 2);
    if (i + 1 < ITER) LOAD_GROUP(g0 + i + 1, nxt);
    // ---- (B) stage + barrier ----------------------------------------------
    xq_s[t]       = xqR[cur][0];
    xq_s[256 + t] = xqR[cur][1];
    xq_s[512 + t] = xqR[cur][2];
    xq_s[768 + t] = xqR[cur][3];
    if (t < 4) b4_s[cur][t] = b4R[cur];
    __syncthreads();
    // ---- convert ea -> bf16 fragments -------------------------------------
    bf16x8 bfr[2];
#pragma unroll
    for (int kk = 0; kk < 2; kk++)
#pragma unroll
      for (int j = 0; j < 4; j++) {
        bfr[kk][j]     = (__bf16)eaR[cur][kk * 2][j];
        bfr[kk][4 + j] = (__bf16)eaR[cur][kk * 2 + 1][j];
      }
    // ---- k_s stage (wave-private, swizzled) -------------------------------
    char* kswW = (char*)k_s + w * 4096;
#pragma unroll
    for (int e = 0; e < 16; e++)
      *(unsigned int*)(kswW + e * 256 + ((4 * l) ^ ((e & 7) << 4))) = kwR[cur][e];
    // ---- dk^T MFMA ---------------------------------------------------------
    f32x4 acc[8];
#pragma unroll
    for (int n = 0; n < 8; n++) acc[n] = (f32x4){0.f, 0.f, 0.f, 0.f};
#pragma unroll
    for (int n = 0; n < 8; n++)
#pragma unroll
      for (int kk = 0; kk < 2; kk++) {
        bf16x8 af = *(const bf16x8*)(wdk_s + ((n * 2 + kk) * 64 + l) * 8);
        acc[n] = __builtin_amdgcn_mfma_f32_16x16x32_bf16(af, bfr[kk], acc[n], 0, 0, 0);
      }
    // ---- phase 1: attention logits + silu ----------------------------------
    const char* kswR = (const char*)k_s + w * 4096;
#pragma unroll
    for (int n = 0; n < 8; n++) {
      const int cb = n * 16 + eh * 4;
      f32x4 qv = *(const f32x4*)&xq_s[512 + w * HID + cb];
      f32x4 bd = *(const f32x4*)&prm_s[cb];
      uint2 kk2 = *(const uint2*)(kswR + el * 256 + ((n * 32 + eh * 8) ^ ((el & 7) << 4)));
      float k0 = __uint_as_float(kk2.x << 16);
      float k1 = __uint_as_float(kk2.x & 0xFFFF0000u);
      float k2 = __uint_as_float(kk2.y << 16);
      float k3 = __uint_as_float(kk2.y & 0xFFFF0000u);
      float d0 = acc[n][0] + bd[0];
      float d1 = acc[n][1] + bd[1];
      float d2 = acc[n][2] + bd[2];
      float d3 = acc[n][3] + bd[3];
      float s = qv[0] * k0 * d0 + qv[1] * k1 * d1 + qv[2] * k2 * d2 + qv[3] * k3 * d3;
      float at = s * __builtin_amdgcn_rcpf(1.0f + __expf(-s));   // silu
      at_s[w * 528 + el * 33 + n * 4 + eh] = at;                 // same-wave
    }
    // ---- phase 2: message accumulation (channel-major) ---------------------
    int hl = l >> 1;
    float macc0 = 0.f, macc1 = 0.f;
#pragma unroll
    for (int e = 0; e < 16; e++) {
      float at = at_s[w * 528 + e * 33 + hl];
      float k0 = __uint_as_float(kwR[cur][e] << 16);
      float k1 = __uint_as_float(kwR[cur][e] & 0xFFFF0000u);
      macc0 = fmaf(k0, at, macc0);
      macc1 = fmaf(k1, at, macc1);
    }
    float2 xv = *(const float2*)&xq_s[w * HID + 2 * l];
    float h10 = xv.x + macc0 * 0.0625f;
    float h11 = xv.y + macc1 * 0.0625f;
    // ---- LayerNorm ----------------------------------------------------------
    float ss = h10 + h11;
    ss += __shfl_xor(ss, 1);  ss += __shfl_xor(ss, 2);  ss += __shfl_xor(ss, 4);
    ss += __shfl_xor(ss, 8);  ss += __shfl_xor(ss, 16); ss += __shfl_xor(ss, 32);
    float mean = ss * (1.0f / HID);
    float dv0 = h10 - mean, dv1 = h11 - mean;
    float vv = dv0 * dv0 + dv1 * dv1;
    vv += __shfl_xor(vv, 1);  vv += __shfl_xor(vv, 2);  vv += __shfl_xor(vv, 4);
    vv += __shfl_xor(vv, 8);  vv += __shfl_xor(vv, 16); vv += __shfl_xor(vv, 32);
    float rstd = rsqrtf(vv * (1.0f / HID) + LN_EPS);
    float2 gv = *(const float2*)&prm_s[HID + 2 * l];
    float2 bv = *(const float2*)&prm_s[2 * HID + 2 * l];
    float2 ho;
    ho.x = xv.x + dv0 * rstd * gv.x + bv.x;
    ho.y = xv.y + dv1 * rstd * gv.y + bv.y;
    *(float2*)&h_s[w * 132 + 2 * l] = ho;
    __syncthreads();
    // ---- cross-iteration run-length aggregation ----------------------------
    if (t < HID) {
#pragma unroll
      for (int nn = 0; nn < 4; nn++) {
        int gph = b4_s[cur][nn];
        if (gph != curG) {
          atomicAdd(&gsum[(curG * NSLOT + slot) * HID + t], accu);
          accu = 0.f;
          curG = gph;
        }
        accu += h_s[nn * 132 + t];
      }
    }
  }
  if (t < HID)
    atomicAdd(&gsum[(curG * NSLOT + slot) * HID + t], accu);
}

// -------------------------------------------------------------- readout -----
__global__ void readout_kernel(const float* __restrict__ gsum,
                               const int* __restrict__ batch,
                               const float* __restrict__ Wout,
                               const float* __restrict__ bout,
                               float* __restrict__ out) {
  int g = blockIdx.x, l = threadIdx.x;
  int lo = 0, hi = N_NODES;
  while (lo < hi) { int mid = (lo + hi) >> 1; if (batch[mid] < g) lo = mid + 1; else hi = mid; }
  int lo2 = lo, hi2 = N_NODES;
  while (lo2 < hi2) { int mid = (lo2 + hi2) >> 1; if (batch[mid] < g + 1) lo2 = mid + 1; else hi2 = mid; }
  int cnt = lo2 - lo; if (cnt < 1) cnt = 1;
  float a0 = 0.f, a1 = 0.f;
#pragma unroll 4
  for (int s = 0; s < NSLOT; s++) {
    const float* row = gsum + ((size_t)g * NSLOT + s) * HID;
    a0 += row[l];
    a1 += row[64 + l];
  }
  float v = a0 * Wout[l] + a1 * Wout[64 + l];
#pragma unroll
  for (int s = 32; s >= 1; s >>= 1) v += __shfl_xor(v, s);
  if (l == 0) out[g] = v / (float)cnt + bout[0];
}

// ---------------------------------------------------------------------------
extern "C" void kernel_launch(void* const* d_in, const int* in_sizes, int n_in,
                              void* d_out, int out_size, void* d_ws, size_t ws_size,
                              hipStream_t stream) {
  const float* x         = (const float*)d_in[0];
  const float* edge_attr = (const float*)d_in[1];
  const float* Wq        = (const float*)d_in[2];
  const float* bq        = (const float*)d_in[3];
  const float* Wkv       = (const float*)d_in[4];
  const float* bkv       = (const float*)d_in[5];
  const float* Wdk       = (const float*)d_in[6];
  const float* bdk       = (const float*)d_in[7];
  const float* ln_in_g   = (const float*)d_in[8];
  const float* ln_in_b   = (const float*)d_in[9];
  const float* ln_out_g  = (const float*)d_in[10];
  const float* ln_out_b  = (const float*)d_in[11];
  const float* Wout      = (const float*)d_in[12];
  const float* bout      = (const float*)d_in[13];
  const int* edge_index  = (const int*)d_in[14];   // [2][E]: src then dst
  const int* batch       = (const int*)d_in[15];
  float* outp = (float*)d_out;

  char* ws = (char*)d_ws;
  float* qbuf          = (float*)ws;                                   // 25.6 MB
  unsigned short* kbuf = (unsigned short*)(ws + 25600000);             // 12.8 MB
  unsigned short* WBf  = (unsigned short*)(ws + 25600000 + 12800000);  // 64 KB
  unsigned short* Wdkf = (unsigned short*)(ws + 25600000 + 12800000 + 65536);
  float* gsum          = (float*)(ws + 25600000 + 12800000 + 65536 + 16384);  // 1 MB

  prep_kernel<<<32, 256, 0, stream>>>(Wq, Wkv, Wdk, WBf, Wdkf, gsum);
  node_kernel<<<(N_NODES + 63) / 64, 256, 0, stream>>>(x, bq, bkv, ln_in_g, ln_in_b,
                                                       WBf, qbuf, kbuf);
  edge_kernel<<<N_NODES / 4 / ITER, 256, 0, stream>>>(x, edge_attr, edge_index, batch,
                                                      bdk, ln_out_g, ln_out_b, qbuf,
                                                      kbuf, Wdkf, gsum);
  readout_kernel<<<NG, 64, 0, stream>>>(gsum, batch, Wout, bout, outp);
}